// Round 6
// baseline (204.345 us; speedup 1.0000x reference)
//
#include <hip/hip_runtime.h>
#include <hip/hip_cooperative_groups.h>

namespace cg = cooperative_groups;

#define Bn 8
#define Xn 2048
#define Yn 2048
#define Hn 1024
#define RPB 8                  // q-rows per block in phase 1
#define NPB (Yn / RPB)         // 256 pe-groups per batch
#define YC 64                  // v-rows per block in phase 2 (R0/R5 proven shape)
#define NCH (Yn / YC)          // 32 chunks per batch
#define GRID (Bn * Yn / RPB)   // 2048 blocks

// Math: softmax over y of (sk[x] + sq[y] + b) == softmax(sq[y]); sk, b cancel.
// Max-subtraction unnecessary: sq ~ N(0,0.5), |sq| < ~4 -> exp in [e^-4,e^4];
// ratio equals max-subtracted softmax to rounding (absmax 1.2e-4, R0-R5).
//
// Topology (R1/R2/R4 lesson): fusing phases per-BLOCK runs ~50 us regardless
// of occupancy/order (even L3-resident: 4 MB fetch, 51.7 us) -- lockstep
// burst/drain. R5's split streams = 203.5 us; the residual overhead is 2
// kernel boundaries. This round: fuse per-LAUNCH with grid.sync() -- phase
// code is byte-identical to R5's proven streams, only the boundaries change.

__global__ __launch_bounds__(256, 8)
void k_all(const float* __restrict__ q, const float* __restrict__ W,
           const float* __restrict__ v, float* __restrict__ pe,
           float* __restrict__ sb, float* __restrict__ o,
           float4* __restrict__ out) {
    const int blk = blockIdx.x;
    const int t = threadIdx.x;
    const int wave = t >> 6, lane = t & 63;
    __shared__ float ps[RPB];
    __shared__ float wred[4];
    __shared__ float pw[YC];

    // ---------- phase 1: pe[row] = exp(q[row,:].Wq), sb = 8-row partial sums,
    // ---------- zero o (2048 blocks x 16 B = full B*H accumulator).
    if (t == 0) ((float4*)o)[blk] = make_float4(0.f, 0.f, 0.f, 0.f);
    {
        const float4* w4 = (const float4*)(W + Hn);   // Wq = W[H:]
        const float4 ww0 = w4[lane];
        const float4 ww1 = w4[lane + 64];
        const float4 ww2 = w4[lane + 128];
        const float4 ww3 = w4[lane + 192];

        const int ra = blk * RPB + wave * 2;          // global row (b*Y + y)
        const float4* qa = (const float4*)(q + (size_t)ra * Hn);
        const float4* qb = qa + (Hn / 4);
        float acca = 0.f, accb = 0.f;
        #pragma unroll
        for (int i = 0; i < 4; ++i) {                 // 8 independent loads in flight
            float4 a  = qa[lane + 64 * i];
            float4 bb = qb[lane + 64 * i];
            float4 w  = (i == 0) ? ww0 : (i == 1) ? ww1 : (i == 2) ? ww2 : ww3;
            acca += a.x * w.x + a.y * w.y + a.z * w.z + a.w * w.w;
            accb += bb.x * w.x + bb.y * w.y + bb.z * w.z + bb.w * w.w;
        }
        #pragma unroll
        for (int off = 32; off > 0; off >>= 1) {
            acca += __shfl_xor(acca, off, 64);
            accb += __shfl_xor(accb, off, 64);
        }
        if (lane == 0) {
            float ea = __expf(acca), eb = __expf(accb);
            pe[ra] = ea; pe[ra + 1] = eb;
            ps[wave * 2] = ea; ps[wave * 2 + 1] = eb;
        }
        __syncthreads();
        if (t == 0) {
            float s = 0.f;
            #pragma unroll
            for (int i = 0; i < RPB; ++i) s += ps[i];
            sb[blk] = s;
        }
    }

    cg::this_grid().sync();

    // ---------- phase 2: o[b,h] += sum_{y in chunk} (pe[b,y]/den_b)*v[b,y,h].
    // R5's proven k_pv on blocks 0..255; others sleep at the next barrier.
    if (blk < NCH * Bn) {
        const int b = blk >> 5;                       // NCH = 32
        const int c = blk & (NCH - 1);
        const int y0 = c * YC;

        float s = sb[b * NPB + t];                    // 256 L2-resident partials
        #pragma unroll
        for (int off = 32; off > 0; off >>= 1) s += __shfl_xor(s, off, 64);
        if (lane == 0) wred[wave] = s;
        __syncthreads();
        const float inv = 1.f / (wred[0] + wred[1] + wred[2] + wred[3]);

        if (t < YC) pw[t] = pe[b * Yn + y0 + t] * inv;
        __syncthreads();

        const float4* v4 = (const float4*)(v + ((size_t)b * Yn + y0) * Hn);
        float4 acc = {0.f, 0.f, 0.f, 0.f};
        #pragma unroll 16
        for (int yy = 0; yy < YC; ++yy) {
            const float p = pw[yy];                   // LDS broadcast (free)
            const float4 vv = v4[(size_t)yy * (Hn / 4) + t];
            acc.x = fmaf(p, vv.x, acc.x);
            acc.y = fmaf(p, vv.y, acc.y);
            acc.z = fmaf(p, vv.z, acc.z);
            acc.w = fmaf(p, vv.w, acc.w);
        }
        float* ob = o + b * Hn + 4 * t;
        atomicAdd(ob + 0, acc.x);
        atomicAdd(ob + 1, acc.y);
        atomicAdd(ob + 2, acc.z);
        atomicAdd(ob + 3, acc.w);
    }

    cg::this_grid().sync();

    // ---------- phase 3: out[b,x,h] = o[b,h] broadcast (4 float4 rows/block).
    const float4* o4 = (const float4*)o;
    #pragma unroll
    for (int j = 0; j < 4; ++j) {
        const size_t i = ((size_t)(blk * 4 + j)) * 256 + t;   // over B*X*H/4
        const int h4 = (int)(i & (Hn / 4 - 1));
        const size_t row = i >> 8;                    // b*X + x
        const int b = (int)(row >> 11);               // X = 2048
        out[i] = o4[b * (Hn / 4) + h4];
    }
}

// ---------- fallback path: R5's proven 3-kernel split (203.5 us) ----------
__global__ __launch_bounds__(256)
void k_pe(const float* __restrict__ q, const float* __restrict__ W,
          float* __restrict__ pe, float* __restrict__ sb,
          float* __restrict__ o) {
    const int blk = blockIdx.x;
    const int t = threadIdx.x;
    const int wave = t >> 6, lane = t & 63;
    __shared__ float ps[RPB];
    if (t == 0) ((float4*)o)[blk] = make_float4(0.f, 0.f, 0.f, 0.f);
    const float4* w4 = (const float4*)(W + Hn);
    const float4 ww0 = w4[lane];
    const float4 ww1 = w4[lane + 64];
    const float4 ww2 = w4[lane + 128];
    const float4 ww3 = w4[lane + 192];
    const int ra = blk * RPB + wave * 2;
    const float4* qa = (const float4*)(q + (size_t)ra * Hn);
    const float4* qb = qa + (Hn / 4);
    float acca = 0.f, accb = 0.f;
    #pragma unroll
    for (int i = 0; i < 4; ++i) {
        float4 a  = qa[lane + 64 * i];
        float4 bb = qb[lane + 64 * i];
        float4 w  = (i == 0) ? ww0 : (i == 1) ? ww1 : (i == 2) ? ww2 : ww3;
        acca += a.x * w.x + a.y * w.y + a.z * w.z + a.w * w.w;
        accb += bb.x * w.x + bb.y * w.y + bb.z * w.z + bb.w * w.w;
    }
    #pragma unroll
    for (int off = 32; off > 0; off >>= 1) {
        acca += __shfl_xor(acca, off, 64);
        accb += __shfl_xor(accb, off, 64);
    }
    if (lane == 0) {
        float ea = __expf(acca), eb = __expf(accb);
        pe[ra] = ea; pe[ra + 1] = eb;
        ps[wave * 2] = ea; ps[wave * 2 + 1] = eb;
    }
    __syncthreads();
    if (t == 0) {
        float s = 0.f;
        #pragma unroll
        for (int i = 0; i < RPB; ++i) s += ps[i];
        sb[blk] = s;
    }
}

__global__ __launch_bounds__(256)
void k_pv(const float* __restrict__ v, const float* __restrict__ pe,
          const float* __restrict__ sb, float* __restrict__ o) {
    const int b = blockIdx.y;
    const int c = blockIdx.x;
    const int y0 = c * YC;
    const int t = threadIdx.x;
    const int wave = t >> 6, lane = t & 63;
    __shared__ float wred[4];
    __shared__ float pw[YC];
    float s = sb[b * NPB + t];
    #pragma unroll
    for (int off = 32; off > 0; off >>= 1) s += __shfl_xor(s, off, 64);
    if (lane == 0) wred[wave] = s;
    __syncthreads();
    const float inv = 1.f / (wred[0] + wred[1] + wred[2] + wred[3]);
    if (t < YC) pw[t] = pe[b * Yn + y0 + t] * inv;
    __syncthreads();
    const float4* v4 = (const float4*)(v + ((size_t)b * Yn + y0) * Hn);
    float4 acc = {0.f, 0.f, 0.f, 0.f};
    #pragma unroll 16
    for (int yy = 0; yy < YC; ++yy) {
        const float p = pw[yy];
        const float4 vv = v4[(size_t)yy * (Hn / 4) + t];
        acc.x = fmaf(p, vv.x, acc.x);
        acc.y = fmaf(p, vv.y, acc.y);
        acc.z = fmaf(p, vv.z, acc.z);
        acc.w = fmaf(p, vv.w, acc.w);
    }
    float* ob = o + b * Hn + 4 * t;
    atomicAdd(ob + 0, acc.x);
    atomicAdd(ob + 1, acc.y);
    atomicAdd(ob + 2, acc.z);
    atomicAdd(ob + 3, acc.w);
}

__global__ void k_bcast(const float* __restrict__ o, float4* __restrict__ out) {
    const size_t i = (size_t)blockIdx.x * blockDim.x + threadIdx.x;
    const int h4 = (int)(i & (Hn / 4 - 1));
    const size_t row = i >> 8;
    const int b = (int)(row >> 11);
    const float4* o4 = (const float4*)o;
    out[i] = o4[b * (Hn / 4) + h4];
}

extern "C" void kernel_launch(void* const* d_in, const int* in_sizes, int n_in,
                              void* d_out, int out_size, void* d_ws, size_t ws_size,
                              hipStream_t stream) {
    const float* q = (const float*)d_in[0];
    // d_in[1] = k : provably unused (cancels in the softmax over y)
    const float* v = (const float*)d_in[2];
    const float* W = (const float*)d_in[3];
    // d_in[4] = b : scalar bias, also cancels
    float* out = (float*)d_out;

    float* pe = (float*)d_ws;                     // B*Y floats   (64 KB)
    float* sb = pe + (size_t)Bn * Yn;             // 2048 floats  (8 KB)
    float* o  = sb + Bn * NPB;                    // B*H floats   (32 KB)

    // One-time capability check (host-only queries; graph-capture-safe).
    static int use_coop = -1;
    if (use_coop < 0) {
        int dev = 0, attr = 0, ncu = 0, nb = 0;
        hipGetDevice(&dev);
        hipDeviceGetAttribute(&attr, hipDeviceAttributeCooperativeLaunch, dev);
        hipDeviceGetAttribute(&ncu, hipDeviceAttributeMultiprocessorCount, dev);
        hipOccupancyMaxActiveBlocksPerMultiprocessor(&nb, k_all, 256, 0);
        use_coop = (attr != 0 && nb * ncu >= GRID) ? 1 : 0;
    }

    if (use_coop) {
        float4* out4 = (float4*)out;
        void* args[] = {(void*)&q, (void*)&W, (void*)&v, (void*)&pe,
                        (void*)&sb, (void*)&o, (void*)&out4};
        hipLaunchCooperativeKernel((void*)k_all, dim3(GRID), dim3(256),
                                   args, 0, stream);
    } else {
        k_pe   <<<GRID, 256, 0, stream>>>(q, W, pe, sb, o);
        k_pv   <<<dim3(NCH, Bn), 256, 0, stream>>>(v, pe, sb, o);
        k_bcast<<<(Bn * (size_t)Xn * Hn / 4) / 256, 256, 0, stream>>>(o, (float4*)out);
    }
}

// Round 7
// 203.934 us; speedup vs baseline: 1.0020x; 1.0020x over previous
//
#include <hip/hip_runtime.h>

#define Bn 8
#define Xn 2048
#define Yn 2048
#define Hn 1024
#define RPB 8                 // rows per k_pe block
#define NPB (Yn / RPB)        // 256 pe-blocks per batch
#define YC 64                 // v-rows per k_pv block (R0/R5 proven shape)
#define NCH (Yn / YC)         // 32 chunks per batch

// FINAL ARTIFACT (verbatim R5, best measured: 203.5 us).
//
// Math: softmax over y of (sk[x] + sq[y] + b) == softmax(sq[y]); sk, b cancel
// (k and the scalar bias are provably unused). Max-subtraction unnecessary:
// sq = q.Wq ~ N(0,0.5), |sq| < ~4 over all rows -> exp in [e^-4, e^4]; the
// ratio equals max-subtracted softmax to rounding (absmax 1.2e-4, R0-R6).
//
// Topology evidence across the session:
//  - per-BLOCK fusion of q-dot -> barrier -> v-stream: ~50 us at any occupancy
//    (17/27/52%), any load order, even with L3-resident inputs (4 MB HBM fetch,
//    51.7 us) -- lockstep phase-coupled burst/drain, 3x confirmed (R1/R2/R4).
//  - per-LAUNCH fusion via grid.sync (R6): neutral (204.3) -- device-wide
//    barrier costs what the inter-kernel gap costs (~3 us), plus a 432-us
//    cold first launch.
//  - split pure streams (this file): each phase runs steady-state near the
//    fill-demonstrated BW ceiling; softmax + reduce + o-zeroing are folded
//    into the two streams (R3->R5: -5.6 us). 192 MiB mandatory traffic.

// K1: pe[row] = exp(q[row,:].Wq); sb[blk] = sum of this block's 8 pe values;
// also zeroes 16 B of o (2048 blocks x 16 B = full B*H accumulator, poison-safe).
__global__ __launch_bounds__(256)
void k_pe(const float* __restrict__ q, const float* __restrict__ W,
          float* __restrict__ pe, float* __restrict__ sb,
          float* __restrict__ o) {
    const int blk = blockIdx.x;
    const int t = threadIdx.x;
    const int wave = t >> 6, lane = t & 63;
    __shared__ float ps[RPB];

    if (t == 0) ((float4*)o)[blk] = make_float4(0.f, 0.f, 0.f, 0.f);

    const float4* w4 = (const float4*)(W + Hn);   // Wq = W[H:]
    const float4 ww0 = w4[lane];
    const float4 ww1 = w4[lane + 64];
    const float4 ww2 = w4[lane + 128];
    const float4 ww3 = w4[lane + 192];

    const int ra = blk * RPB + wave * 2;          // global row (b*Y + y)
    const float4* qa = (const float4*)(q + (size_t)ra * Hn);
    const float4* qb = qa + (Hn / 4);
    float acca = 0.f, accb = 0.f;
    #pragma unroll
    for (int i = 0; i < 4; ++i) {                 // 8 independent loads in flight
        float4 a  = qa[lane + 64 * i];
        float4 bb = qb[lane + 64 * i];
        float4 w  = (i == 0) ? ww0 : (i == 1) ? ww1 : (i == 2) ? ww2 : ww3;
        acca += a.x * w.x + a.y * w.y + a.z * w.z + a.w * w.w;
        accb += bb.x * w.x + bb.y * w.y + bb.z * w.z + bb.w * w.w;
    }
    #pragma unroll
    for (int off = 32; off > 0; off >>= 1) {
        acca += __shfl_xor(acca, off, 64);
        accb += __shfl_xor(accb, off, 64);
    }
    if (lane == 0) {
        float ea = __expf(acca), eb = __expf(accb);
        pe[ra] = ea; pe[ra + 1] = eb;
        ps[wave * 2] = ea; ps[wave * 2 + 1] = eb;
    }
    __syncthreads();
    if (t == 0) {
        float s = 0.f;
        #pragma unroll
        for (int i = 0; i < RPB; ++i) s += ps[i];
        sb[blk] = s;
    }
}

// K2: o[b,h] += sum_{y in chunk} (pe[b,y]/den_b) * v[b,y,h].
// 256 blocks, 64-deep independent float4 ILP, atomicAdd epilogue.
// Prologue reduces den_b from sb (256 L2-resident values).
__global__ __launch_bounds__(256)
void k_pv(const float* __restrict__ v, const float* __restrict__ pe,
          const float* __restrict__ sb, float* __restrict__ o) {
    const int b = blockIdx.y;
    const int c = blockIdx.x;
    const int y0 = c * YC;
    const int t = threadIdx.x;
    const int wave = t >> 6, lane = t & 63;
    __shared__ float wred[4];
    __shared__ float pw[YC];

    float s = sb[b * NPB + t];                    // 256 L2-resident partials
    #pragma unroll
    for (int off = 32; off > 0; off >>= 1) s += __shfl_xor(s, off, 64);
    if (lane == 0) wred[wave] = s;
    __syncthreads();
    const float inv = 1.f / (wred[0] + wred[1] + wred[2] + wred[3]);

    if (t < YC) pw[t] = pe[b * Yn + y0 + t] * inv;   // normalized weights
    __syncthreads();

    const float4* v4 = (const float4*)(v + ((size_t)b * Yn + y0) * Hn);
    float4 acc = {0.f, 0.f, 0.f, 0.f};
    #pragma unroll 16
    for (int yy = 0; yy < YC; ++yy) {
        const float p = pw[yy];                   // LDS broadcast (free)
        const float4 vv = v4[(size_t)yy * (Hn / 4) + t];
        acc.x = fmaf(p, vv.x, acc.x);
        acc.y = fmaf(p, vv.y, acc.y);
        acc.z = fmaf(p, vv.z, acc.z);
        acc.w = fmaf(p, vv.w, acc.w);
    }
    float* ob = o + b * Hn + 4 * t;
    atomicAdd(ob + 0, acc.x);
    atomicAdd(ob + 1, acc.y);
    atomicAdd(ob + 2, acc.z);
    atomicAdd(ob + 3, acc.w);
}

// K3: out[b,x,h] = o[b,h] broadcast; float4 stores, o L2-resident.
__global__ void k_bcast(const float* __restrict__ o, float4* __restrict__ out) {
    const size_t i = (size_t)blockIdx.x * blockDim.x + threadIdx.x;  // B*X*H/4
    const int h4 = (int)(i & (Hn / 4 - 1));
    const size_t row = i >> 8;                        // b*X + x
    const int b = (int)(row >> 11);                   // X = 2048
    const float4* o4 = (const float4*)o;
    out[i] = o4[b * (Hn / 4) + h4];
}

extern "C" void kernel_launch(void* const* d_in, const int* in_sizes, int n_in,
                              void* d_out, int out_size, void* d_ws, size_t ws_size,
                              hipStream_t stream) {
    const float* q = (const float*)d_in[0];
    // d_in[1] = k : provably unused (cancels in the softmax over y)
    const float* v = (const float*)d_in[2];
    const float* W = (const float*)d_in[3];
    // d_in[4] = b : scalar bias, also cancels
    float* out = (float*)d_out;

    float* pe = (float*)d_ws;                     // B*Y floats   (64 KB)
    float* sb = pe + (size_t)Bn * Yn;             // 2048 floats  (8 KB)
    float* o  = sb + Bn * NPB;                    // B*H floats   (32 KB)

    k_pe   <<<Bn * Yn / RPB, 256, 0, stream>>>(q, W, pe, sb, o);
    k_pv   <<<dim3(NCH, Bn), 256, 0, stream>>>(v, pe, sb, o);
    k_bcast<<<(Bn * (size_t)Xn * Hn / 4) / 256, 256, 0, stream>>>(o, (float4*)out);
}